// Round 2
// baseline (253.242 us; speedup 1.0000x reference)
//
#include <hip/hip_runtime.h>

// LearnedQueryAttention: B=8, L=4096, KD=512, ED=1024, H=8. All I/O fp32.
// Raw-reshape semantics: head h owns the contiguous flat slab
// f = h*(L+1)*(C/H) + row*(C/H) + d of per-batch [X_flat | bias]; only
// f >= L*C touches the bias token (head 7, rows 4089..4096). The bias
// boundary is row-aligned for both K (64/row) and V (128/row), so a
// per-ROW pointer select is exact.
//
// Round notes (this revision):
//  - R1 post-mortem: removing barriers alone gave -8%; counters show
//    latency-bound (HBM 16%, VALU 7.5%, occ 64%) => intra-block phase
//    convoy. This round: WAVE-INDEPENDENT chunks. Each wave owns 32 rows:
//    Phase A keeps exp-weights in REGISTERS (e[8] per 16-lane group, all
//    lanes hold the value), Phase B broadcasts them via __shfl. No LDS
//    score buffer, no A->B barrier. Single tail barrier merges the 4
//    waves' V-partials so kernel 2 keeps its NC=32 shape.
//  - m=0 softmax frame retained (scores |t|<~1, exp safe, shift-invariant):
//    no max pass, partials sum directly in the combine.
//  - Row 4096 handled analytically in kernel 2; kernel 1 covers rows
//    0..4095 with compile-time trip counts.
#define BATCH 8
#define LSEQ  4096
#define LP    4097
#define KDIM  512
#define EDIM  1024
#define NH    8
#define DK    64
#define DV    128
#define NG    64          // B*H groups
#define NC    32          // chunk-groups per group (128 rows each)
#define LN_EPS 1e-5f

typedef float floatx4 __attribute__((ext_vector_type(4)));

// ---------------------------------------------------------------------------
// Kernel 1: per (group g, chunk-group cg of 128 rows): each of the 4 waves
// independently handles 32 rows (scores in regs -> shfl-broadcast -> AV
// accumulate). One barrier total (cross-wave partial merge).
// Grid (32, 64), 256 threads.
// ---------------------------------------------------------------------------
__global__ __launch_bounds__(256) void lqa_fused_kernel(
    const float* __restrict__ keys, const float* __restrict__ k_bias,
    const float* __restrict__ values, const float* __restrict__ v_bias,
    const float* __restrict__ query, const float* __restrict__ sw,
    const float* __restrict__ sb, float* __restrict__ partials,
    float* __restrict__ zstats)
{
    const int cg = blockIdx.x;               // 0..31
    const int g  = blockIdx.y;               // 0..63
    const int b = g >> 3, h = g & 7;
    const int t = threadIdx.x;
    const int w = t >> 6;                    // wave 0..3
    const int lane = t & 63;
    const int row0 = cg * 128 + w * 32;      // this wave's 32 rows

    __shared__ float red[4 * DV];
    __shared__ float zred[4];

    // ---- Phase A: 4 groups x 16 lanes; group gid does rows 4j+gid ----
    // All 16 lanes of a group end up holding e[j] (butterfly gives every
    // lane the full dot; every lane computes the same exp).
    const int gid = lane >> 4, l16 = lane & 15;
    const floatx4 q = *reinterpret_cast<const floatx4*>(query + h * DK + l16 * 4);
    const float* kp = keys + (long long)b * (LSEQ * KDIM);
    const int fheadk = h * (LP * DK);
    const float* wptr = sw + h * LP;
    const float* bptr = sb + h * LP;
    float e[8];
    float z = 0.f;
#pragma unroll
    for (int j = 0; j < 8; ++j) {
        const int row = row0 + 4 * j + gid;          // groups cover 4 consec rows
        const int f = fheadk + row * DK;             // row-aligned select
        const float* rowp = (f < LSEQ * KDIM) ? (kp + f)
                                              : (k_bias + (f - LSEQ * KDIM));
        const floatx4 k = *reinterpret_cast<const floatx4*>(rowp + l16 * 4);
        float s = q.x * k.x + q.y * k.y + q.z * k.z + q.w * k.w;
        s += __shfl_xor(s, 1);
        s += __shfl_xor(s, 2);
        s += __shfl_xor(s, 4);
        s += __shfl_xor(s, 8);
        const float ev = __expf(s * wptr[row] + bptr[row]);  // m=0 frame
        e[j] = ev;
        z += ev;
    }
    // wave z (sum of 32 rows): fold the 4 groups
    z += __shfl_xor(z, 16);
    z += __shfl_xor(z, 32);

    // ---- Phase B: lanes 0-31 take even row of each pair, 32-63 odd ----
    const int hi = (lane >> 5) & 1;
    const int d0 = (lane & 31) * 4;
    const float* vp = values + (long long)b * (LSEQ * EDIM);
    const int fheadv = h * (LP * DV);
    float a0 = 0.f, a1 = 0.f, a2 = 0.f, a3 = 0.f;
#pragma unroll
    for (int j = 0; j < 8; ++j) {
        // rows 4j+hi (weight from group hi) and 4j+2+hi (group 2+hi)
        const float e0 = __shfl(e[j], 16 * hi, 64);
        const float e1 = __shfl(e[j], 16 * (2 + hi), 64);
        {
            const int row = row0 + 4 * j + hi;
            const int f = fheadv + row * DV;         // row-aligned select
            const float* rowp = (f < LSEQ * EDIM) ? (vp + f)
                                                  : (v_bias + (f - LSEQ * EDIM));
            const floatx4 v = *reinterpret_cast<const floatx4*>(rowp + d0);
            a0 += e0 * v.x; a1 += e0 * v.y; a2 += e0 * v.z; a3 += e0 * v.w;
        }
        {
            const int row = row0 + 4 * j + 2 + hi;
            const int f = fheadv + row * DV;
            const float* rowp = (f < LSEQ * EDIM) ? (vp + f)
                                                  : (v_bias + (f - LSEQ * EDIM));
            const floatx4 v = *reinterpret_cast<const floatx4*>(rowp + d0);
            a0 += e1 * v.x; a1 += e1 * v.y; a2 += e1 * v.z; a3 += e1 * v.w;
        }
    }
    // fold even/odd halves: all lanes now hold dims (lane&31)*4 summed
    a0 += __shfl_xor(a0, 32);
    a1 += __shfl_xor(a1, 32);
    a2 += __shfl_xor(a2, 32);
    a3 += __shfl_xor(a3, 32);

    // ---- tail: merge the 4 waves' partials (single barrier) ----
    if (lane < 32) {
        float* dst = red + w * DV + d0;
        dst[0] = a0; dst[1] = a1; dst[2] = a2; dst[3] = a3;
    }
    if (lane == 0) zred[w] = z;
    __syncthreads();
    if (t < DV) {
        const float sum = red[t] + red[DV + t] + red[2 * DV + t] + red[3 * DV + t];
        partials[((long long)(g * NC + cg)) * DV + t] = sum;
    } else if (t == DV) {
        zstats[g * NC + cg] = zred[0] + zred[1] + zred[2] + zred[3];
    }
}

// ---------------------------------------------------------------------------
// Kernel 2: combine (m=0 frame: plain sums) + row-4096 token + LayerNorm.
// One block per batch, 1024 threads (one per embed dim). Unchanged from R1.
// ---------------------------------------------------------------------------
__global__ __launch_bounds__(1024) void lqa_combine_ln_kernel(
    const float* __restrict__ partials, const float* __restrict__ zstats,
    const float* __restrict__ keys, const float* __restrict__ values,
    const float* __restrict__ k_bias, const float* __restrict__ v_bias,
    const float* __restrict__ query, const float* __restrict__ sw,
    const float* __restrict__ sb, const float* __restrict__ gamma,
    const float* __restrict__ beta, float* __restrict__ out)
{
    const int b = blockIdx.x;
    const int t = threadIdx.x;
    __shared__ float zh[NH];                 // per-head Z (finally incl. e_bias)
    __shared__ float eb[NH];                 // row-4096 exp weight per head
    __shared__ float r1[16], r2[16];

    // S1 (waves 0-3): Z partial = sum_c z_c, 32 chunks reduced by shuffles
    if (t < 256) {
        float zv = zstats[(b * NH + (t >> 5)) * NC + (t & 31)];
        zv += __shfl_xor(zv, 1);
        zv += __shfl_xor(zv, 2);
        zv += __shfl_xor(zv, 4);
        zv += __shfl_xor(zv, 8);
        zv += __shfl_xor(zv, 16);
        if ((t & 31) == 0) zh[t >> 5] = zv;
    } else if (t < 384) {
        // S2 (waves 4-5): row-4096 score per head: 16-lane dot + exp
        const int tt = t - 256;
        const int h = tt >> 4, l16 = tt & 15;
        const floatx4 q = *reinterpret_cast<const floatx4*>(query + h * DK + l16 * 4);
        const int fk = h * (LP * DK) + LSEQ * DK;       // flat row 4096
        const float* kr = (fk < LSEQ * KDIM)
            ? keys + (long long)b * (LSEQ * KDIM) + fk
            : k_bias + (fk - LSEQ * KDIM);
        const floatx4 k = *reinterpret_cast<const floatx4*>(kr + l16 * 4);
        float s = q.x * k.x + q.y * k.y + q.z * k.z + q.w * k.w;
        s += __shfl_xor(s, 1);
        s += __shfl_xor(s, 2);
        s += __shfl_xor(s, 4);
        s += __shfl_xor(s, 8);
        if (l16 == 0) eb[h] = __expf(s * sw[h * LP + LSEQ] + sb[h * LP + LSEQ]);
    }
    __syncthreads();
    if (t < NH) zh[t] += eb[t];
    __syncthreads();

    // S3: each thread owns one embed dim e = t = h*128 + d
    const int h = t >> 7, d = t & 127;
    const float* src = partials + ((long long)((b * NH + h) * NC)) * DV + d;
    float sum = 0.f;
#pragma unroll
    for (int c = 0; c < NC; ++c) sum += src[c * DV];
    const int fv = h * (LP * DV) + LSEQ * DV + d;       // flat row 4096
    const float v4 = (fv < LSEQ * EDIM)
        ? values[(long long)b * (LSEQ * EDIM) + fv]
        : v_bias[fv - LSEQ * EDIM];
    const float av = (sum + eb[h] * v4) / zh[h];

    // S4: LayerNorm over 1024 dims: wave shuffle reduce + 16-wave LDS combine
    float s1 = av, s2 = av * av;
    s1 += __shfl_xor(s1, 1);  s2 += __shfl_xor(s2, 1);
    s1 += __shfl_xor(s1, 2);  s2 += __shfl_xor(s2, 2);
    s1 += __shfl_xor(s1, 4);  s2 += __shfl_xor(s2, 4);
    s1 += __shfl_xor(s1, 8);  s2 += __shfl_xor(s2, 8);
    s1 += __shfl_xor(s1, 16); s2 += __shfl_xor(s2, 16);
    s1 += __shfl_xor(s1, 32); s2 += __shfl_xor(s2, 32);
    if ((t & 63) == 0) { r1[t >> 6] = s1; r2[t >> 6] = s2; }
    __syncthreads();
    float fs1 = 0.f, fs2 = 0.f;
#pragma unroll
    for (int i = 0; i < 16; ++i) { fs1 += r1[i]; fs2 += r2[i]; }
    const float mean = fs1 * (1.0f / EDIM);
    const float var = fs2 * (1.0f / EDIM) - mean * mean;
    const float inv = rsqrtf(var + LN_EPS);
    out[(long long)b * EDIM + t] = (av - mean) * inv * gamma[t] + beta[t];
}

// ---------------------------------------------------------------------------
extern "C" void kernel_launch(void* const* d_in, const int* in_sizes, int n_in,
                              void* d_out, int out_size, void* d_ws, size_t ws_size,
                              hipStream_t stream) {
    const float* keys   = (const float*)d_in[0];
    const float* values = (const float*)d_in[1];
    const float* query  = (const float*)d_in[2];
    const float* k_bias = (const float*)d_in[3];
    const float* v_bias = (const float*)d_in[4];
    const float* sw     = (const float*)d_in[5];
    const float* sb     = (const float*)d_in[6];
    const float* gamma  = (const float*)d_in[7];
    const float* beta   = (const float*)d_in[8];
    float* out = (float*)d_out;

    // ws layout (floats): partials[64][32][128] | zstats[64*32] (~1.05 MB)
    float* ws = (float*)d_ws;
    float* partials = ws;
    float* zstats = ws + (long long)NG * NC * DV;

    lqa_fused_kernel<<<dim3(NC, NG), 256, 0, stream>>>(
        keys, k_bias, values, v_bias, query, sw, sb, partials, zstats);
    lqa_combine_ln_kernel<<<BATCH, 1024, 0, stream>>>(
        partials, zstats, keys, values, k_bias, v_bias, query, sw, sb,
        gamma, beta, out);
}

// Round 3
// 249.463 us; speedup vs baseline: 1.0151x; 1.0151x over previous
//
#include <hip/hip_runtime.h>

// LearnedQueryAttention: B=8, L=4096, KD=512, ED=1024, H=8. All I/O fp32.
// Raw-reshape semantics: head h owns the contiguous flat slab
// f = h*(L+1)*(C/H) + row*(C/H) + d of per-batch [X_flat | bias]; only
// f >= L*C touches the bias token (head 7, rows 4089..4096). Row-aligned
// pointer select is exact for both K (64 f/row) and V (128 f/row).
//
// Round notes (this revision):
//  - R2 post-mortem: 3 structurally different kernels all ~78us, HBM 16%,
//    VALU 7%, VGPR=36 => latency-bound, MLP~1 (compiler serialized
//    load->shuffle-chain->load). Fix: BATCH-ISSUE loads into registers.
//    * __launch_bounds__(256,4): 128-VGPR budget (occupancy was 52% anyway)
//    * Phase A: all 8 K loads + w/b loads issued before any dot/shuffle;
//      butterfly levels interleaved across 8 independent rows (chains
//      pipeline in the LDS unit instead of serializing).
//    * Phase B: all 16 V loads issued first; e-broadcasts (ds_bpermute)
//      execute UNDER the V-load latency; then pure FMA.
//  - m=0 softmax frame retained (|scores|<~1): no max pass, partials sum
//    directly. Row 4096 handled analytically in kernel 2.
#define BATCH 8
#define LSEQ  4096
#define LP    4097
#define KDIM  512
#define EDIM  1024
#define NH    8
#define DK    64
#define DV    128
#define NG    64          // B*H groups
#define NC    32          // chunk-groups per group (128 rows each)
#define LN_EPS 1e-5f

typedef float floatx4 __attribute__((ext_vector_type(4)));

// ---------------------------------------------------------------------------
// Kernel 1: per (group g, chunk-group cg of 128 rows); each of 4 waves owns
// 32 rows end-to-end in registers. One barrier (cross-wave partial merge).
// Grid (32, 64), 256 threads, 4 blocks/CU.
// ---------------------------------------------------------------------------
__global__ __launch_bounds__(256, 4) void lqa_fused_kernel(
    const float* __restrict__ keys, const float* __restrict__ k_bias,
    const float* __restrict__ values, const float* __restrict__ v_bias,
    const float* __restrict__ query, const float* __restrict__ sw,
    const float* __restrict__ sb, float* __restrict__ partials,
    float* __restrict__ zstats)
{
    const int cg = blockIdx.x;               // 0..31
    const int g  = blockIdx.y;               // 0..63
    const int b = g >> 3, h = g & 7;
    const int t = threadIdx.x;
    const int w = t >> 6;                    // wave 0..3
    const int lane = t & 63;
    const int row0 = cg * 128 + w * 32;      // this wave's 32 rows

    __shared__ float red[4 * DV];
    __shared__ float zred[4];

    // ---- Phase A: 4 groups x 16 lanes; group gid handles rows 4j+gid ----
    const int gid = lane >> 4, l16 = lane & 15;
    const floatx4 q = *reinterpret_cast<const floatx4*>(query + h * DK + l16 * 4);
    const float* kp = keys + (long long)b * (LSEQ * KDIM);
    const int fheadk = h * (LP * DK);
    const float* wptr = sw + h * LP;
    const float* bptr = sb + h * LP;

    // batch-issue: 8 K-row loads + 8 w + 8 b loads, no dependent ops between
    floatx4 kv[8];
    float wv[8], bv[8];
#pragma unroll
    for (int j = 0; j < 8; ++j) {
        const int row = row0 + 4 * j + gid;
        const int f = fheadk + row * DK;                // row-aligned select
        const float* rowp = (f < LSEQ * KDIM) ? (kp + f)
                                              : (k_bias + (f - LSEQ * KDIM));
        kv[j] = *reinterpret_cast<const floatx4*>(rowp + l16 * 4);
        wv[j] = wptr[row];
        bv[j] = bptr[row];
    }
    float s[8];
#pragma unroll
    for (int j = 0; j < 8; ++j)
        s[j] = q.x * kv[j].x + q.y * kv[j].y + q.z * kv[j].z + q.w * kv[j].w;
    // butterfly: 4 levels, interleaved across 8 independent rows (pipelines)
#pragma unroll
    for (int j = 0; j < 8; ++j) s[j] += __shfl_xor(s[j], 1);
#pragma unroll
    for (int j = 0; j < 8; ++j) s[j] += __shfl_xor(s[j], 2);
#pragma unroll
    for (int j = 0; j < 8; ++j) s[j] += __shfl_xor(s[j], 4);
#pragma unroll
    for (int j = 0; j < 8; ++j) s[j] += __shfl_xor(s[j], 8);
    float e[8];
    float z = 0.f;
#pragma unroll
    for (int j = 0; j < 8; ++j) {
        e[j] = __expf(s[j] * wv[j] + bv[j]);            // m=0 frame
        z += e[j];
    }
    z += __shfl_xor(z, 16);
    z += __shfl_xor(z, 32);

    // ---- Phase B: lanes 0-31 even row of each pair, 32-63 odd ----
    const int hi = (lane >> 5) & 1;
    const int d0 = (lane & 31) * 4;
    const float* vp = values + (long long)b * (LSEQ * EDIM);
    const int fheadv = h * (LP * DV);

    // batch-issue all 16 V loads (rows 4j+hi and 4j+2+hi)
    floatx4 v0[8], v1[8];
#pragma unroll
    for (int j = 0; j < 8; ++j) {
        const int fA = fheadv + (row0 + 4 * j + hi) * DV;
        const float* rpA = (fA < LSEQ * EDIM) ? (vp + fA)
                                              : (v_bias + (fA - LSEQ * EDIM));
        v0[j] = *reinterpret_cast<const floatx4*>(rpA + d0);
        const int fB = fheadv + (row0 + 4 * j + 2 + hi) * DV;
        const float* rpB = (fB < LSEQ * EDIM) ? (vp + fB)
                                              : (v_bias + (fB - LSEQ * EDIM));
        v1[j] = *reinterpret_cast<const floatx4*>(rpB + d0);
    }
    // broadcasts execute under the V-load latency
    float e0[8], e1[8];
#pragma unroll
    for (int j = 0; j < 8; ++j) e0[j] = __shfl(e[j], 16 * hi, 64);
#pragma unroll
    for (int j = 0; j < 8; ++j) e1[j] = __shfl(e[j], 16 * (2 + hi), 64);

    float a0 = 0.f, a1 = 0.f, a2 = 0.f, a3 = 0.f;
#pragma unroll
    for (int j = 0; j < 8; ++j) {
        a0 += e0[j] * v0[j].x; a1 += e0[j] * v0[j].y;
        a2 += e0[j] * v0[j].z; a3 += e0[j] * v0[j].w;
        a0 += e1[j] * v1[j].x; a1 += e1[j] * v1[j].y;
        a2 += e1[j] * v1[j].z; a3 += e1[j] * v1[j].w;
    }
    // fold even/odd halves: all lanes hold dims (lane&31)*4 summed
    a0 += __shfl_xor(a0, 32);
    a1 += __shfl_xor(a1, 32);
    a2 += __shfl_xor(a2, 32);
    a3 += __shfl_xor(a3, 32);

    // ---- tail: merge the 4 waves' partials (single barrier) ----
    if (lane < 32) {
        float* dst = red + w * DV + d0;
        dst[0] = a0; dst[1] = a1; dst[2] = a2; dst[3] = a3;
    }
    if (lane == 0) zred[w] = z;
    __syncthreads();
    if (t < DV) {
        const float sum = red[t] + red[DV + t] + red[2 * DV + t] + red[3 * DV + t];
        partials[((long long)(g * NC + cg)) * DV + t] = sum;
    } else if (t == DV) {
        zstats[g * NC + cg] = zred[0] + zred[1] + zred[2] + zred[3];
    }
}

// ---------------------------------------------------------------------------
// Kernel 2: combine (m=0 frame: plain sums) + row-4096 token + LayerNorm.
// One block per batch, 1024 threads (one per embed dim). Unchanged from R2.
// ---------------------------------------------------------------------------
__global__ __launch_bounds__(1024) void lqa_combine_ln_kernel(
    const float* __restrict__ partials, const float* __restrict__ zstats,
    const float* __restrict__ keys, const float* __restrict__ values,
    const float* __restrict__ k_bias, const float* __restrict__ v_bias,
    const float* __restrict__ query, const float* __restrict__ sw,
    const float* __restrict__ sb, const float* __restrict__ gamma,
    const float* __restrict__ beta, float* __restrict__ out)
{
    const int b = blockIdx.x;
    const int t = threadIdx.x;
    __shared__ float zh[NH];                 // per-head Z (finally incl. e_bias)
    __shared__ float eb[NH];                 // row-4096 exp weight per head
    __shared__ float r1[16], r2[16];

    // S1 (waves 0-3): Z partial = sum_c z_c, 32 chunks reduced by shuffles
    if (t < 256) {
        float zv = zstats[(b * NH + (t >> 5)) * NC + (t & 31)];
        zv += __shfl_xor(zv, 1);
        zv += __shfl_xor(zv, 2);
        zv += __shfl_xor(zv, 4);
        zv += __shfl_xor(zv, 8);
        zv += __shfl_xor(zv, 16);
        if ((t & 31) == 0) zh[t >> 5] = zv;
    } else if (t < 384) {
        // S2 (waves 4-5): row-4096 score per head: 16-lane dot + exp
        const int tt = t - 256;
        const int h = tt >> 4, l16 = tt & 15;
        const floatx4 q = *reinterpret_cast<const floatx4*>(query + h * DK + l16 * 4);
        const int fk = h * (LP * DK) + LSEQ * DK;       // flat row 4096
        const float* kr = (fk < LSEQ * KDIM)
            ? keys + (long long)b * (LSEQ * KDIM) + fk
            : k_bias + (fk - LSEQ * KDIM);
        const floatx4 k = *reinterpret_cast<const floatx4*>(kr + l16 * 4);
        float s = q.x * k.x + q.y * k.y + q.z * k.z + q.w * k.w;
        s += __shfl_xor(s, 1);
        s += __shfl_xor(s, 2);
        s += __shfl_xor(s, 4);
        s += __shfl_xor(s, 8);
        if (l16 == 0) eb[h] = __expf(s * sw[h * LP + LSEQ] + sb[h * LP + LSEQ]);
    }
    __syncthreads();
    if (t < NH) zh[t] += eb[t];
    __syncthreads();

    // S3: each thread owns one embed dim e = t = h*128 + d
    const int h = t >> 7, d = t & 127;
    const float* src = partials + ((long long)((b * NH + h) * NC)) * DV + d;
    float sum = 0.f;
#pragma unroll
    for (int c = 0; c < NC; ++c) sum += src[c * DV];
    const int fv = h * (LP * DV) + LSEQ * DV + d;       // flat row 4096
    const float v4 = (fv < LSEQ * EDIM)
        ? values[(long long)b * (LSEQ * EDIM) + fv]
        : v_bias[fv - LSEQ * EDIM];
    const float av = (sum + eb[h] * v4) / zh[h];

    // S4: LayerNorm over 1024 dims: wave shuffle reduce + 16-wave LDS combine
    float s1 = av, s2 = av * av;
    s1 += __shfl_xor(s1, 1);  s2 += __shfl_xor(s2, 1);
    s1 += __shfl_xor(s1, 2);  s2 += __shfl_xor(s2, 2);
    s1 += __shfl_xor(s1, 4);  s2 += __shfl_xor(s2, 4);
    s1 += __shfl_xor(s1, 8);  s2 += __shfl_xor(s2, 8);
    s1 += __shfl_xor(s1, 16); s2 += __shfl_xor(s2, 16);
    s1 += __shfl_xor(s1, 32); s2 += __shfl_xor(s2, 32);
    if ((t & 63) == 0) { r1[t >> 6] = s1; r2[t >> 6] = s2; }
    __syncthreads();
    float fs1 = 0.f, fs2 = 0.f;
#pragma unroll
    for (int i = 0; i < 16; ++i) { fs1 += r1[i]; fs2 += r2[i]; }
    const float mean = fs1 * (1.0f / EDIM);
    const float var = fs2 * (1.0f / EDIM) - mean * mean;
    const float inv = rsqrtf(var + LN_EPS);
    out[(long long)b * EDIM + t] = (av - mean) * inv * gamma[t] + beta[t];
}

// ---------------------------------------------------------------------------
extern "C" void kernel_launch(void* const* d_in, const int* in_sizes, int n_in,
                              void* d_out, int out_size, void* d_ws, size_t ws_size,
                              hipStream_t stream) {
    const float* keys   = (const float*)d_in[0];
    const float* values = (const float*)d_in[1];
    const float* query  = (const float*)d_in[2];
    const float* k_bias = (const float*)d_in[3];
    const float* v_bias = (const float*)d_in[4];
    const float* sw     = (const float*)d_in[5];
    const float* sb     = (const float*)d_in[6];
    const float* gamma  = (const float*)d_in[7];
    const float* beta   = (const float*)d_in[8];
    float* out = (float*)d_out;

    // ws layout (floats): partials[64][32][128] | zstats[64*32] (~1.05 MB)
    float* ws = (float*)d_ws;
    float* partials = ws;
    float* zstats = ws + (long long)NG * NC * DV;

    lqa_fused_kernel<<<dim3(NC, NG), 256, 0, stream>>>(
        keys, k_bias, values, v_bias, query, sw, sb, partials, zstats);
    lqa_combine_ln_kernel<<<BATCH, 1024, 0, stream>>>(
        partials, zstats, keys, values, k_bias, v_bias, query, sw, sb,
        gamma, beta, out);
}